// Round 4
// baseline (545.919 us; speedup 1.0000x reference)
//
#include <hip/hip_runtime.h>

// SelfAttnPool: B=32, T=4096, F=512, U=512 (fp32 in/out)
//   scores[b,t] = tanh(x[b,t,:]@W + b) @ V   (u never materialized)
//   a = softmax_T(scores); out[b,f] = sum_t a[b,t]*x[b,t,f]
//
// R8: m201-style phased K-loop. R7 post-mortem: 2 waves/SIMD barrier-locked
// 2-phase structure -> ~32% MfmaUtil structural ceiling. Changes:
//  - B staged via global_load_lds (linear copy of pre-swizzled W workspace;
//    wave-uniform LDS dst + lane*16B). Kills 8 ds_writes + 32 staging VGPRs.
//  - K32 iter split into 4 MFMA clusters of 12 (h-half x cf-quad); B frags
//    for cluster s+1 ds_read before cluster s (double-set regs) so the LDS
//    pipe runs under the MFMA pipe within each wave.
//  - s_setprio(1) around each MFMA cluster (T5; phase role-split now exists).
//  - ONE __syncthreads per iter; staging + A loads issued a full iter ahead
//    so the barrier's vmcnt drain is free.
// Numerics: same cvt_hilo + per-acc term order (hh,lh,hl; k asc) as R5-R7.

#define XT 4096
#define XF 512
#define XU 512

typedef __attribute__((ext_vector_type(8))) short short8;
typedef __attribute__((ext_vector_type(16))) float f32x16;

__device__ inline void cvt_hilo(float x, unsigned short &h, unsigned short &l) {
  unsigned u = __builtin_bit_cast(unsigned, x);
  h = (unsigned short)(u >> 16);                       // truncated bf16 hi
  float hf = __builtin_bit_cast(float, u & 0xFFFF0000u);
  float lo = x - hf;                                   // exact residual
  l = (unsigned short)(__builtin_bit_cast(unsigned, lo) >> 16);
}

__device__ inline float tanh_fast(float z) {
  float e = __expf(2.0f * z);
  return 1.0f - 2.0f * __builtin_amdgcn_rcpf(e + 1.0f);
}

__device__ inline void load_lds_16B(const unsigned short *gsrc,
                                    unsigned short *ldst) {
  __builtin_amdgcn_global_load_lds(
      (const __attribute__((address_space(1))) unsigned int *)gsrc,
      (__attribute__((address_space(3))) unsigned int *)ldst, 16, 0, 0);
}

// ---- W pre-conversion: fp32 [512 k][512 n] -> bf16 hi/lo, fragment-ready:
// whi/wlo: [slice s(32)][chunk16B: t(16)*64 + g(2)*32 + l(32)][j(8)]
// element = W[k = s*16 + g*8 + j][n = t*32 + l]
__global__ void wconv_kernel(const float *__restrict__ W,
                             unsigned short *__restrict__ whi,
                             unsigned short *__restrict__ wlo) {
  int t2 = blockIdx.x * 256 + threadIdx.x;  // 32768 threads
  int l = t2 & 31;
  int g = (t2 >> 5) & 1;
  int t = (t2 >> 6) & 15;
  int s = t2 >> 10;
  short8 hv, lv;
#pragma unroll
  for (int j = 0; j < 8; ++j) {
    unsigned short h, lo;
    cvt_hilo(W[(size_t)(s * 16 + g * 8 + j) * XU + t * 32 + l], h, lo);
    hv[j] = (short)h;
    lv[j] = (short)lo;
  }
  size_t off = (size_t)s * 8192 + t * 512 + g * 256 + l * 8;
  *(short8 *)(whi + off) = hv;
  *(short8 *)(wlo + off) = lv;
}

#define MFMA(a, b, c) __builtin_amdgcn_mfma_f32_32x32x16_bf16(a, b, c, 0, 0, 0)

// read 8 B-frags (cfg quad, hi+lo) of half H into reg set SET (all literal)
#define READSUB(BASE, H, CFG, SET)                                  \
  {                                                                 \
    const unsigned short *bp_ = (BASE) + (H)*16384 + (CFG)*2048 + fbase; \
    Fh##SET[0] = *(const short8 *)(bp_);                            \
    Fh##SET[1] = *(const short8 *)(bp_ + 512);                      \
    Fh##SET[2] = *(const short8 *)(bp_ + 1024);                     \
    Fh##SET[3] = *(const short8 *)(bp_ + 1536);                     \
    Fl##SET[0] = *(const short8 *)(bp_ + 8192);                     \
    Fl##SET[1] = *(const short8 *)(bp_ + 8704);                     \
    Fl##SET[2] = *(const short8 *)(bp_ + 9216);                     \
    Fl##SET[3] = *(const short8 *)(bp_ + 9728);                     \
  }

// 12-MFMA cluster: half H (A frags), col quad CFG, frag set SET
#define CLUSTER(H, CFG, SET)                                        \
  {                                                                 \
    short8 aH_ = (H) ? ah1 : ah0;                                   \
    short8 aL_ = (H) ? al1 : al0;                                   \
    __builtin_amdgcn_s_setprio(1);                                  \
    acc[(CFG)*4 + 0] = MFMA(aH_, Fh##SET[0], acc[(CFG)*4 + 0]);     \
    acc[(CFG)*4 + 0] = MFMA(aL_, Fh##SET[0], acc[(CFG)*4 + 0]);     \
    acc[(CFG)*4 + 0] = MFMA(aH_, Fl##SET[0], acc[(CFG)*4 + 0]);     \
    acc[(CFG)*4 + 1] = MFMA(aH_, Fh##SET[1], acc[(CFG)*4 + 1]);     \
    acc[(CFG)*4 + 1] = MFMA(aL_, Fh##SET[1], acc[(CFG)*4 + 1]);     \
    acc[(CFG)*4 + 1] = MFMA(aH_, Fl##SET[1], acc[(CFG)*4 + 1]);     \
    acc[(CFG)*4 + 2] = MFMA(aH_, Fh##SET[2], acc[(CFG)*4 + 2]);     \
    acc[(CFG)*4 + 2] = MFMA(aL_, Fh##SET[2], acc[(CFG)*4 + 2]);     \
    acc[(CFG)*4 + 2] = MFMA(aH_, Fl##SET[2], acc[(CFG)*4 + 2]);     \
    acc[(CFG)*4 + 3] = MFMA(aH_, Fh##SET[3], acc[(CFG)*4 + 3]);     \
    acc[(CFG)*4 + 3] = MFMA(aL_, Fh##SET[3], acc[(CFG)*4 + 3]);     \
    acc[(CFG)*4 + 3] = MFMA(aH_, Fl##SET[3], acc[(CFG)*4 + 3]);     \
    __builtin_amdgcn_s_setprio(0);                                  \
  }

// ---- fused GEMM + tanh + (.@V) + chunk-local softmax + weighted pooling
// block: 512 thr = 8 waves; tile 128 rows x 512 cols.
// wave = (rs 0..3, c 0..1): rows rs*32..+32, cols c*256..+256.
__global__ __launch_bounds__(512, 2)
void gemm_scores_kernel(const float *__restrict__ x,
                        const unsigned short *__restrict__ whi,
                        const unsigned short *__restrict__ wlo,
                        const float *__restrict__ bias,
                        const float *__restrict__ V,
                        float *__restrict__ partial,
                        float *__restrict__ pstats) {
  // B staging: per buf one K32 slice, 4 regions x 8192 ushorts:
  // region r = h*2 + hl; inside = wconv slice layout [t*512+g*256+l*8+j].
  __shared__ unsigned short Bsh[2][32768];  // 128 KB
  __shared__ float scb[256];   // [c 2][row 128] col-half scores
  __shared__ float sarr[128];  // chunk scores
  __shared__ float warr[128];  // chunk-local softmax weights e^{s-m}
  __shared__ float red[1536];  // pooling cross-rowgroup reduction

  const int tid = threadIdx.x;
  const int lane = tid & 63;
  const int wave = tid >> 6;
  const int rs = wave & 3;    // row strip (32 rows)
  const int c = wave >> 2;    // col half (256 cols)
  const int l31 = lane & 31;
  const int half = lane >> 5;
  const size_t rowbase = (size_t)blockIdx.x * 128;

  f32x16 acc[8];
#pragma unroll
  for (int cf = 0; cf < 8; ++cf)
#pragma unroll
    for (int r = 0; r < 16; ++r) acc[cf][r] = 0.f;

  // A: row = rowbase + rs*32 + l31 ; k = j*32 + h*16 + half*8 + jj
  const float *xr = x + (rowbase + rs * 32 + l31) * XF + half * 8;
  const int fbase = c * 4096 + lane * 8;  // frag ushort offset within region

  // staging assignment: wave -> region w2 = wave>>1, half (wave&1)
  const int w2 = wave >> 1;
  const unsigned short *gsrc0 = ((w2 & 1) ? wlo : whi) +
                                (size_t)(w2 >> 1) * 8192 + (wave & 1) * 4096 +
                                lane * 8;
  unsigned short *ldsW = &Bsh[0][0] + w2 * 8192 + (wave & 1) * 4096;
  unsigned short *Bsh0 = &Bsh[0][0];

  short8 Fh0[4], Fl0[4], Fh1[4], Fl1[4];
  float4 xa0, xa1, xa2, xa3;
  short8 ah0, al0, ah1, al1;

  // ---- prologue: stage slice 0 (DMA), load A slice 0
#pragma unroll
  for (int i = 0; i < 8; ++i) load_lds_16B(gsrc0 + i * 512, ldsW + i * 512);
  xa0 = *(const float4 *)(xr);
  xa1 = *(const float4 *)(xr + 4);
  xa2 = *(const float4 *)(xr + 16);
  xa3 = *(const float4 *)(xr + 20);
  __syncthreads();
  READSUB(Bsh0, 0, 0, 0);  // sub0 frags -> set0

#pragma unroll 1
  for (int j = 0; j < 16; ++j) {
    const unsigned short *bsC = Bsh0 + (j & 1) * 32768;

    // convert A(j) (loaded last iter; drained at barrier)
    {
      float v0[8] = {xa0.x, xa0.y, xa0.z, xa0.w, xa1.x, xa1.y, xa1.z, xa1.w};
      float v1[8] = {xa2.x, xa2.y, xa2.z, xa2.w, xa3.x, xa3.y, xa3.z, xa3.w};
#pragma unroll
      for (int jj = 0; jj < 8; ++jj) {
        unsigned short h, lo;
        cvt_hilo(v0[jj], h, lo);
        ah0[jj] = (short)h; al0[jj] = (short)lo;
        cvt_hilo(v1[jj], h, lo);
        ah1[jj] = (short)h; al1[jj] = (short)lo;
      }
    }

    // issue next-iter staging DMA + A loads (land during this iter's MFMAs)
    if (j < 15) {
      const unsigned short *gs = gsrc0 + (size_t)(j + 1) * 16384;
      unsigned short *ls = ldsW + ((j + 1) & 1) * 32768;
#pragma unroll
      for (int i = 0; i < 8; ++i) load_lds_16B(gs + i * 512, ls + i * 512);
      xa0 = *(const float4 *)(xr + (j + 1) * 32);
      xa1 = *(const float4 *)(xr + (j + 1) * 32 + 4);
      xa2 = *(const float4 *)(xr + (j + 1) * 32 + 16);
      xa3 = *(const float4 *)(xr + (j + 1) * 32 + 20);
    }

    // 4 sub-phases: read frags for sub s+1, MFMA cluster for sub s
    READSUB(bsC, 0, 1, 1);
    CLUSTER(0, 0, 0);
    READSUB(bsC, 1, 0, 0);
    CLUSTER(0, 1, 1);
    READSUB(bsC, 1, 1, 1);
    CLUSTER(1, 0, 0);
    CLUSTER(1, 1, 1);

    __syncthreads();
    if (j < 15) {
      const unsigned short *bsN = Bsh0 + ((j + 1) & 1) * 32768;
      READSUB(bsN, 0, 0, 0);  // next iter sub0 -> set0
    }
  }

  // ---- score epilogue: sc[row] = sum over this wave's 256 cols
  // C/D 32x32: col n = c*256 + cf*32 + l31 ; row = (r&3)+8*(r>>2)+4*half
  float sc[16];
#pragma unroll
  for (int r = 0; r < 16; ++r) sc[r] = 0.f;
#pragma unroll
  for (int cf = 0; cf < 8; ++cf) {
    int n = c * 256 + cf * 32 + l31;
    float vv = V[n];
    float bb = bias[n];
#pragma unroll
    for (int r = 0; r < 16; ++r)
      sc[r] += tanh_fast(acc[cf][r] + bb) * vv;
  }
#pragma unroll
  for (int m = 1; m <= 16; m <<= 1) {
#pragma unroll
    for (int r = 0; r < 16; ++r) sc[r] += __shfl_xor(sc[r], m, 64);
  }
  if (l31 == 0) {
#pragma unroll
    for (int r = 0; r < 16; ++r) {
      int row = rs * 32 + (r & 3) + 8 * (r >> 2) + 4 * half;
      scb[c * 128 + row] = sc[r];
    }
  }
  __syncthreads();

  // ---- chunk-local softmax over 128 rows
  if (tid < 128) sarr[tid] = scb[tid] + scb[128 + tid];
  __syncthreads();
  float mloc = -1e30f;
#pragma unroll 8
  for (int i = 0; i < 128; ++i) mloc = fmaxf(mloc, sarr[i]);
  if (tid < 128) warr[tid] = __expf(sarr[tid] - mloc);
  __syncthreads();

  // l_c = sum warr : 64-lane shuffle reduce
  float lsum = 0.f;
  if (tid < 64) {
    lsum = warr[tid] + warr[tid + 64];
#pragma unroll
    for (int m = 1; m < 64; m <<= 1) lsum += __shfl_xor(lsum, m, 64);
  }

  // ---- weighted pooling over own (L2-hot) tile: 4 row-groups x 128 col4s
  const int rg = tid >> 7;   // 0..3 -> rows rg*32..+32
  const int c4 = tid & 127;  // float4 column
  const float *xp = x + rowbase * XF;
  float4 pa = {0.f, 0.f, 0.f, 0.f};
#pragma unroll 8
  for (int i = 0; i < 32; ++i) {
    int r = rg * 32 + i;
    float4 v = *(const float4 *)(xp + (size_t)r * XF + c4 * 4);
    float wv = warr[r];
    pa.x += wv * v.x;
    pa.y += wv * v.y;
    pa.z += wv * v.z;
    pa.w += wv * v.w;
  }
  if (rg > 0) {
    float *rp = red + (rg - 1) * 512 + c4 * 4;
    rp[0] = pa.x; rp[1] = pa.y; rp[2] = pa.z; rp[3] = pa.w;
  }
  __syncthreads();
  if (rg == 0) {
    const float *r0 = red + c4 * 4;
    float4 o;
    o.x = pa.x + r0[0] + r0[512] + r0[1024];
    o.y = pa.y + r0[1] + r0[513] + r0[1025];
    o.z = pa.z + r0[2] + r0[514] + r0[1026];
    o.w = pa.w + r0[3] + r0[515] + r0[1027];
    *(float4 *)(partial + (size_t)blockIdx.x * 512 + c4 * 4) = o;
  }
  if (tid == 0) {
    pstats[blockIdx.x * 2] = mloc;
    pstats[blockIdx.x * 2 + 1] = lsum;
  }
}

// ---- combine: out[b,f] = sum_c e^{m_c-M} partial[c][f] / (sum_c e^{m_c-M} l_c)
__global__ __launch_bounds__(512)
void combine_kernel(const float *__restrict__ partial,
                    const float *__restrict__ pstats,
                    float *__restrict__ out) {
  int b = blockIdx.x;
  int f = threadIdx.x;
  __shared__ float ml[32], ll[32];
  if (f < 32) {
    ml[f] = pstats[(b * 32 + f) * 2];
    ll[f] = pstats[(b * 32 + f) * 2 + 1];
  }
  __syncthreads();
  float M = -1e30f;
#pragma unroll
  for (int c = 0; c < 32; ++c) M = fmaxf(M, ml[c]);
  float L = 0.f;
#pragma unroll
  for (int c = 0; c < 32; ++c) L += __expf(ml[c] - M) * ll[c];
  float acc = 0.f;
#pragma unroll
  for (int c = 0; c < 32; ++c)
    acc += __expf(ml[c] - M) * partial[(size_t)(b * 32 + c) * 512 + f];
  out[b * XF + f] = acc / L;
}

extern "C" void kernel_launch(void *const *d_in, const int *in_sizes, int n_in,
                              void *d_out, int out_size, void *d_ws,
                              size_t ws_size, hipStream_t stream) {
  const float *x = (const float *)d_in[0];
  const float *W = (const float *)d_in[1];
  const float *bias = (const float *)d_in[2];
  const float *V = (const float *)d_in[3];
  float *out = (float *)d_out;

  // workspace: whi 512KB | wlo 512KB | partial 2MB | pstats 8KB
  unsigned short *whi = (unsigned short *)d_ws;
  unsigned short *wlo = whi + 262144;
  float *partial = (float *)((char *)d_ws + 1048576);
  float *pstats = (float *)((char *)d_ws + 1048576 + 2097152);

  wconv_kernel<<<128, 256, 0, stream>>>(W, whi, wlo);
  gemm_scores_kernel<<<1024, 512, 0, stream>>>(x, whi, wlo, bias, V, partial,
                                               pstats);
  combine_kernel<<<32, 512, 0, stream>>>(partial, pstats, out);
}